// Round 1
// baseline (292.772 us; speedup 1.0000x reference)
//
#include <hip/hip_runtime.h>

// MHA: b=2, n=2048, c=1024, h=16, d=64. All GEMMs in bf16 MFMA, f32 accum.
// ws layout (48MB needed): qb(8M) kb(8M) vb(8M) w*b(4x2M) Qh(8M) Kh(8M);
//   Vh reuses kb, AO reuses qb.

typedef float f32x4 __attribute__((ext_vector_type(4)));
typedef __bf16 bf16x8 __attribute__((ext_vector_type(8)));

#define BB 2
#define SEQ 2048
#define CH 1024
#define NH 16
#define HD 64
#define TOK (BB * SEQ)

__device__ __forceinline__ unsigned short f2b(float f) {
  unsigned int u = __float_as_uint(f);
  u = (u + 0x7FFFu + ((u >> 16) & 1u)) >> 16;  // RNE
  return (unsigned short)u;
}

__device__ __forceinline__ void gload16(const void* g, void* l) {
  __builtin_amdgcn_global_load_lds(
      (const __attribute__((address_space(1))) unsigned int*)g,
      (__attribute__((address_space(3))) unsigned int*)l, 16, 0, 0);
}

// ---------------- f32 -> bf16 conversion ----------------
struct CvtArgs {
  const float* src[7];
  unsigned short* dst[7];
  int n4[7];
};

__global__ __launch_bounds__(256) void cvt_kernel(CvtArgs a) {
  const int s = blockIdx.y;
  const int n4 = a.n4[s];
  const float4* __restrict__ src = (const float4*)a.src[s];
  unsigned short* __restrict__ dst = a.dst[s];
  const int stride = gridDim.x * blockDim.x;
  for (int i = blockIdx.x * blockDim.x + threadIdx.x; i < n4; i += stride) {
    float4 w = src[i];
    ushort4 o;
    o.x = f2b(w.x); o.y = f2b(w.y); o.z = f2b(w.z); o.w = f2b(w.w);
    *(ushort4*)(dst + 4 * (size_t)i) = o;
  }
}

// ---------------- GEMM: X[4096,1024] @ W^T[1024,1024] + bias ----------------
// mode 0: out bf16 head-layout [bh][n][d], pre-scaled by 0.125 (Q)
// mode 1: out bf16 head-layout (K, V)
// mode 2: out f32 flat [4096][1024] (final projection)
__global__ __launch_bounds__(256) void proj_kernel(
    const unsigned short* __restrict__ X, const unsigned short* __restrict__ W,
    const float* __restrict__ bias, unsigned short* __restrict__ outb,
    float* __restrict__ outf, int mode) {
  __shared__ __align__(16) unsigned char smem[16384];
  unsigned char* Al = smem;
  unsigned char* Bl = smem + 8192;
  const int tid = threadIdx.x;
  const int wid = tid >> 6, lane = tid & 63;
  const int wm = wid >> 1, wn = wid & 1;
  const int mt = blockIdx.x, nt = blockIdx.y;
  const int l15 = lane & 15, l4 = lane >> 4;

  f32x4 acc[4][4] = {};

  for (int k0 = 0; k0 < CH; k0 += 32) {
#pragma unroll
    for (int is = 0; is < 2; ++is) {
      const int p = (wid * 2 + is) * 1024 + lane * 16;
      const int row = p >> 6;
      const int cole = (p & 63) >> 1;
      gload16(X + (size_t)(mt * 128 + row) * CH + k0 + cole, Al + (wid * 2 + is) * 1024);
      gload16(W + (size_t)(nt * 128 + row) * CH + k0 + cole, Bl + (wid * 2 + is) * 1024);
    }
    __syncthreads();
    bf16x8 af[4], bfr[4];
#pragma unroll
    for (int mi = 0; mi < 4; ++mi)
      af[mi] = *(const bf16x8*)(Al + (wm * 64 + mi * 16 + l15) * 64 + l4 * 16);
#pragma unroll
    for (int nj = 0; nj < 4; ++nj)
      bfr[nj] = *(const bf16x8*)(Bl + (wn * 64 + nj * 16 + l15) * 64 + l4 * 16);
#pragma unroll
    for (int mi = 0; mi < 4; ++mi)
#pragma unroll
      for (int nj = 0; nj < 4; ++nj)
        acc[mi][nj] = __builtin_amdgcn_mfma_f32_16x16x32_bf16(af[mi], bfr[nj], acc[mi][nj], 0, 0, 0);
    __syncthreads();
  }

  const int row0 = mt * 128 + wm * 64;
  const int col0 = nt * 128 + wn * 64;
#pragma unroll
  for (int nj = 0; nj < 4; ++nj) {
    const int col = col0 + nj * 16 + l15;
    const float bv = bias[col];
#pragma unroll
    for (int mi = 0; mi < 4; ++mi) {
#pragma unroll
      for (int r = 0; r < 4; ++r) {
        const int row = row0 + mi * 16 + l4 * 4 + r;
        float v = acc[mi][nj][r] + bv;
        if (mode == 0) v *= 0.125f;  // attention scale folded into Q (exact pow2)
        if (mode <= 1) {
          const int b = row >> 11, n = row & (SEQ - 1);
          const int h = col >> 6, d = col & 63;
          outb[(((size_t)(b * NH + h) * SEQ + n) << 6) + d] = f2b(v);
        } else {
          outf[(size_t)row * CH + col] = v;
        }
      }
    }
  }
}

// ---------------- flash attention ----------------
// block: (qt, bh); 4 waves; each wave owns 32 Q rows. K-tile = 64 keys.
__global__ __launch_bounds__(256) void attn_kernel(
    const unsigned short* __restrict__ Qh, const unsigned short* __restrict__ Kh,
    const unsigned short* __restrict__ Vh, unsigned short* __restrict__ AO) {
  __shared__ __align__(16) unsigned char smem[35840];
  unsigned char* Kl = smem;          // [64][128B], XOR-swizzled content
  unsigned char* VT = smem + 8192;   // [64 d][144B] (padded rows)
  unsigned char* Pl = smem + 17408;  // 4 waves x [32][144B]; Q staged here once
  const int tid = threadIdx.x, wid = tid >> 6, lane = tid & 63;
  const int l15 = lane & 15, l4 = lane >> 4;
  const int qt = blockIdx.x, bh = blockIdx.y;
  const unsigned short* Qb = Qh + (size_t)bh * SEQ * HD;
  const unsigned short* Kb = Kh + (size_t)bh * SEQ * HD;
  const unsigned short* Vb = Vh + (size_t)bh * SEQ * HD;

  // stage Q tile (128 rows x 64 d, 16KB) into Pl region, then move to regs
#pragma unroll
  for (int is = 0; is < 4; ++is) {
    const int off = wid * 4096 + is * 1024;
    gload16(Qb + qt * 128 * HD + ((off + lane * 16) >> 1), Pl + off);
  }
  __syncthreads();
  bf16x8 qf[2][2];
#pragma unroll
  for (int mi = 0; mi < 2; ++mi)
#pragma unroll
    for (int kk = 0; kk < 2; ++kk)
      qf[mi][kk] = *(const bf16x8*)(Pl + (wid * 32 + mi * 16 + l15) * 128 + kk * 64 + l4 * 16);
  __syncthreads();  // everyone done reading Q before Pl is reused for P

  f32x4 O[2][4] = {};
  float mrow[2][4], lrow[2][4];
#pragma unroll
  for (int mi = 0; mi < 2; ++mi)
#pragma unroll
    for (int r = 0; r < 4; ++r) { mrow[mi][r] = -1e30f; lrow[mi][r] = 0.f; }

  unsigned char* Pw = Pl + wid * 4608;

  for (int j0 = 0; j0 < SEQ; j0 += 64) {
    // stage K tile with pre-swizzled global source (LDS holds swizzled layout)
#pragma unroll
    for (int is = 0; is < 2; ++is) {
      const int p = wid * 2048 + is * 1024 + lane * 16;
      const int srcoff = (p & ~127) | ((p & 127) ^ (((p >> 7) & 7) << 4));
      gload16(Kb + j0 * HD + (srcoff >> 1), Kl + wid * 2048 + is * 1024);
    }
    // V tile -> regs (coalesced), transposed into VT after the barrier
    uint4 vreg[2];
#pragma unroll
    for (int is = 0; is < 2; ++is) {
      const int p = is * 4096 + tid * 16;
      vreg[is] = *(const uint4*)((const unsigned char*)(Vb + j0 * HD) + p);
    }
    __syncthreads();  // K in LDS, V in regs; prev-iter VT/P reads drained
#pragma unroll
    for (int is = 0; is < 2; ++is) {
      const int p = is * 4096 + tid * 16;
      const int j = p >> 7, d0 = (p & 127) >> 1;
      const unsigned short* vv = (const unsigned short*)&vreg[is];
#pragma unroll
      for (int jj = 0; jj < 8; ++jj)
        *(unsigned short*)(VT + (d0 + jj) * 144 + j * 2) = vv[jj];
    }

    // S = Q @ K^T  (Q pre-scaled by 0.125)
    f32x4 S[2][4] = {};
#pragma unroll
    for (int kk = 0; kk < 2; ++kk) {
#pragma unroll
      for (int nj = 0; nj < 4; ++nj) {
        const int krow = nj * 16 + l15;
        const bf16x8 kf =
            *(const bf16x8*)(Kl + krow * 128 + ((kk * 64 + l4 * 16) ^ ((krow & 7) << 4)));
#pragma unroll
        for (int mi = 0; mi < 2; ++mi)
          S[mi][nj] = __builtin_amdgcn_mfma_f32_16x16x32_bf16(qf[mi][kk], kf, S[mi][nj], 0, 0, 0);
      }
    }

    // online softmax (wave-parallel: 16-lane xor reductions)
#pragma unroll
    for (int mi = 0; mi < 2; ++mi) {
#pragma unroll
      for (int r = 0; r < 4; ++r) {
        float nm = fmaxf(fmaxf(S[mi][0][r], S[mi][1][r]), fmaxf(S[mi][2][r], S[mi][3][r]));
        nm = fmaxf(nm, __shfl_xor(nm, 1));
        nm = fmaxf(nm, __shfl_xor(nm, 2));
        nm = fmaxf(nm, __shfl_xor(nm, 4));
        nm = fmaxf(nm, __shfl_xor(nm, 8));
        const float mnew = fmaxf(mrow[mi][r], nm);
        const float alpha = exp2f((mrow[mi][r] - mnew) * 1.44269504f);
        mrow[mi][r] = mnew;
        float rs = 0.f;
#pragma unroll
        for (int nj = 0; nj < 4; ++nj) {
          const float pv = exp2f((S[mi][nj][r] - mnew) * 1.44269504f);
          S[mi][nj][r] = pv;
          rs += pv;
        }
        rs += __shfl_xor(rs, 1);
        rs += __shfl_xor(rs, 2);
        rs += __shfl_xor(rs, 4);
        rs += __shfl_xor(rs, 8);
        lrow[mi][r] = lrow[mi][r] * alpha + rs;
#pragma unroll
        for (int nf = 0; nf < 4; ++nf) O[mi][nf][r] *= alpha;
      }
    }

    // P (bf16) -> per-wave LDS buffer, re-read as MFMA A-fragments
#pragma unroll
    for (int mi = 0; mi < 2; ++mi)
#pragma unroll
      for (int nj = 0; nj < 4; ++nj)
#pragma unroll
        for (int r = 0; r < 4; ++r)
          *(unsigned short*)(Pw + (mi * 16 + l4 * 4 + r) * 144 + (nj * 16 + l15) * 2) =
              f2b(S[mi][nj][r]);
    __syncthreads();  // VT writes visible to all waves

    // O += P @ V
#pragma unroll
    for (int kk = 0; kk < 2; ++kk) {
      bf16x8 pa[2];
#pragma unroll
      for (int mi = 0; mi < 2; ++mi)
        pa[mi] = *(const bf16x8*)(Pw + (mi * 16 + l15) * 144 + kk * 64 + l4 * 16);
#pragma unroll
      for (int nf = 0; nf < 4; ++nf) {
        const bf16x8 vf = *(const bf16x8*)(VT + (nf * 16 + l15) * 144 + kk * 64 + l4 * 16);
#pragma unroll
        for (int mi = 0; mi < 2; ++mi)
          O[mi][nf] = __builtin_amdgcn_mfma_f32_16x16x32_bf16(pa[mi], vf, O[mi][nf], 0, 0, 0);
      }
    }
  }

  // epilogue: O /= l, write bf16 to [b][n][h*64+d]
  const int b = bh >> 4, h = bh & 15;
#pragma unroll
  for (int mi = 0; mi < 2; ++mi) {
#pragma unroll
    for (int nf = 0; nf < 4; ++nf) {
      const int d = nf * 16 + l15;
#pragma unroll
      for (int r = 0; r < 4; ++r) {
        const int n = qt * 128 + wid * 32 + mi * 16 + l4 * 4 + r;
        const float v = O[mi][nf][r] / lrow[mi][r];
        AO[((size_t)(b * SEQ + n)) * CH + h * HD + d] = f2b(v);
      }
    }
  }
}

extern "C" void kernel_launch(void* const* d_in, const int* in_sizes, int n_in,
                              void* d_out, int out_size, void* d_ws, size_t ws_size,
                              hipStream_t stream) {
  (void)in_sizes; (void)n_in; (void)out_size; (void)ws_size;
  const float* q  = (const float*)d_in[0];
  const float* k  = (const float*)d_in[1];
  const float* v  = (const float*)d_in[2];
  const float* wq = (const float*)d_in[3];
  const float* bq = (const float*)d_in[4];
  const float* wk = (const float*)d_in[5];
  const float* bk = (const float*)d_in[6];
  const float* wv = (const float*)d_in[7];
  const float* bv = (const float*)d_in[8];
  const float* wo = (const float*)d_in[9];
  const float* bo = (const float*)d_in[10];

  unsigned char* ws = (unsigned char*)d_ws;
  const size_t MB8 = 8u << 20;
  unsigned short* qb  = (unsigned short*)(ws + 0 * MB8);
  unsigned short* kb  = (unsigned short*)(ws + 1 * MB8);
  unsigned short* vb  = (unsigned short*)(ws + 2 * MB8);
  unsigned short* wqb = (unsigned short*)(ws + 3 * MB8);
  unsigned short* wkb = (unsigned short*)(ws + 3 * MB8 + 1 * 2097152);
  unsigned short* wvb = (unsigned short*)(ws + 3 * MB8 + 2 * 2097152);
  unsigned short* wob = (unsigned short*)(ws + 3 * MB8 + 3 * 2097152);
  unsigned short* Qh  = (unsigned short*)(ws + 4 * MB8);
  unsigned short* Kh  = (unsigned short*)(ws + 5 * MB8);
  unsigned short* Vhd = kb;  // kb dead after proj K
  unsigned short* AO  = qb;  // qb dead after proj Q
  float* out = (float*)d_out;

  CvtArgs ca;
  ca.src[0] = q;  ca.dst[0] = qb;  ca.n4[0] = TOK * CH / 4;
  ca.src[1] = k;  ca.dst[1] = kb;  ca.n4[1] = TOK * CH / 4;
  ca.src[2] = v;  ca.dst[2] = vb;  ca.n4[2] = TOK * CH / 4;
  ca.src[3] = wq; ca.dst[3] = wqb; ca.n4[3] = CH * CH / 4;
  ca.src[4] = wk; ca.dst[4] = wkb; ca.n4[4] = CH * CH / 4;
  ca.src[5] = wv; ca.dst[5] = wvb; ca.n4[5] = CH * CH / 4;
  ca.src[6] = wo; ca.dst[6] = wob; ca.n4[6] = CH * CH / 4;
  cvt_kernel<<<dim3(1024, 7), 256, 0, stream>>>(ca);

  proj_kernel<<<dim3(32, 8), 256, 0, stream>>>(qb, wqb, bq, Qh, nullptr, 0);
  proj_kernel<<<dim3(32, 8), 256, 0, stream>>>(kb, wkb, bk, Kh, nullptr, 1);
  proj_kernel<<<dim3(32, 8), 256, 0, stream>>>(vb, wvb, bv, Vhd, nullptr, 1);

  attn_kernel<<<dim3(16, 32), 256, 0, stream>>>(Qh, Kh, Vhd, AO);

  proj_kernel<<<dim3(32, 8), 256, 0, stream>>>(AO, wob, bo, nullptr, out, 2);
}

// Round 2
// 210.983 us; speedup vs baseline: 1.3877x; 1.3877x over previous
//
#include <hip/hip_runtime.h>

// MHA b=2 n=2048 c=1024 h=16 d=64. bf16 MFMA everywhere, f32 accum.
// ws (48MB): qb(8M) kb(8M) vb(8M) w*(4x2M) Qh(8M) Kh(8M); Vt=kb, AO=qb.

typedef float f32x4 __attribute__((ext_vector_type(4)));
typedef __bf16 bf16x8 __attribute__((ext_vector_type(8)));

#define SEQ 2048
#define CH 1024
#define NH 16
#define HD 64
#define TOK 4096
// 0.125 (d^-1/2) * log2(e): fold softmax base-2 conversion into Q
#define QSCALE 0.18033688011112042f

__device__ __forceinline__ unsigned short f2b(float f) {
  unsigned int u = __float_as_uint(f);
  u = (u + 0x7FFFu + ((u >> 16) & 1u)) >> 16;  // RNE
  return (unsigned short)u;
}

__device__ __forceinline__ void gload16(const void* g, void* l) {
  __builtin_amdgcn_global_load_lds(
      (const __attribute__((address_space(1))) unsigned int*)g,
      (__attribute__((address_space(3))) unsigned int*)l, 16, 0, 0);
}

// ---------------- f32 -> bf16 conversion ----------------
struct CvtArgs {
  const float* src[7];
  unsigned short* dst[7];
  int n4[7];
};

__global__ __launch_bounds__(256) void cvt_kernel(CvtArgs a) {
  const int s = blockIdx.y;
  const int n4 = a.n4[s];
  const float4* __restrict__ src = (const float4*)a.src[s];
  unsigned short* __restrict__ dst = a.dst[s];
  const int stride = gridDim.x * blockDim.x;
  for (int i = blockIdx.x * blockDim.x + threadIdx.x; i < n4; i += stride) {
    float4 w = src[i];
    ushort4 o;
    o.x = f2b(w.x); o.y = f2b(w.y); o.z = f2b(w.z); o.w = f2b(w.w);
    *(ushort4*)(dst + 4 * (size_t)i) = o;
  }
}

// ---------------- GEMM: X[4096,1024] @ W^T + bias ----------------
// mode 0: bf16 head layout [bh][n][d], scaled by QSCALE (Q)
// mode 1: bf16 head layout (K)
// mode 2: f32 flat [4096][1024] (output projection)
// mode 3: bf16 transposed head layout [bh][d][n] (V^T)
__device__ __forceinline__ void proj_body(
    unsigned char* smem, const unsigned short* __restrict__ X,
    const unsigned short* __restrict__ W, const float* __restrict__ bias,
    unsigned short* __restrict__ outb, float* __restrict__ outf,
    const int mode, const int mt, const int nt) {
  unsigned char* Al = smem;
  unsigned char* Bl = smem + 8192;
  const int tid = threadIdx.x;
  const int wid = tid >> 6, lane = tid & 63;
  const int wm = wid >> 1, wn = wid & 1;
  const int l15 = lane & 15, l4 = lane >> 4;

  f32x4 acc[4][4] = {};

  for (int k0 = 0; k0 < CH; k0 += 32) {
#pragma unroll
    for (int is = 0; is < 2; ++is) {
      const int p = (wid * 2 + is) * 1024 + lane * 16;
      const int row = p >> 6;
      const int cole = (p & 63) >> 1;
      gload16(X + (size_t)(mt * 128 + row) * CH + k0 + cole, Al + (wid * 2 + is) * 1024);
      gload16(W + (size_t)(nt * 128 + row) * CH + k0 + cole, Bl + (wid * 2 + is) * 1024);
    }
    __syncthreads();
    bf16x8 af[4], bfr[4];
#pragma unroll
    for (int mi = 0; mi < 4; ++mi)
      af[mi] = *(const bf16x8*)(Al + (wm * 64 + mi * 16 + l15) * 64 + l4 * 16);
#pragma unroll
    for (int nj = 0; nj < 4; ++nj)
      bfr[nj] = *(const bf16x8*)(Bl + (wn * 64 + nj * 16 + l15) * 64 + l4 * 16);
#pragma unroll
    for (int mi = 0; mi < 4; ++mi)
#pragma unroll
      for (int nj = 0; nj < 4; ++nj)
        acc[mi][nj] = __builtin_amdgcn_mfma_f32_16x16x32_bf16(af[mi], bfr[nj], acc[mi][nj], 0, 0, 0);
    __syncthreads();
  }

  const int row0 = mt * 128 + wm * 64;
  const int col0 = nt * 128 + wn * 64;
#pragma unroll
  for (int nj = 0; nj < 4; ++nj) {
    const int col = col0 + nj * 16 + l15;
    const float bv = bias[col];
    const int h = col >> 6, d = col & 63;
    if (mode == 3) {
      // V^T: pack 4 consecutive n per (mi,nj)
#pragma unroll
      for (int mi = 0; mi < 4; ++mi) {
        const int row = row0 + mi * 16 + l4 * 4;
        const int b = row >> 11, n = row & (SEQ - 1);
        ushort4 o;
        o.x = f2b(acc[mi][nj][0] + bv);
        o.y = f2b(acc[mi][nj][1] + bv);
        o.z = f2b(acc[mi][nj][2] + bv);
        o.w = f2b(acc[mi][nj][3] + bv);
        *(ushort4*)(outb + ((size_t)(b * NH + h) * HD + d) * SEQ + n) = o;
      }
    } else {
#pragma unroll
      for (int mi = 0; mi < 4; ++mi) {
#pragma unroll
        for (int r = 0; r < 4; ++r) {
          const int row = row0 + mi * 16 + l4 * 4 + r;
          float v = acc[mi][nj][r] + bv;
          if (mode == 0) v *= QSCALE;
          if (mode == 2) {
            outf[(size_t)row * CH + col] = v;
          } else {
            const int b = row >> 11, n = row & (SEQ - 1);
            outb[(((size_t)(b * NH + h) * SEQ + n) << 6) + d] = f2b(v);
          }
        }
      }
    }
  }
}

struct ProjArgs {
  const unsigned short* X[2];
  const unsigned short* W[2];
  const float* bias[2];
  unsigned short* outb[2];
  float* outf;
  int mode[2];
};

__global__ __launch_bounds__(256) void proj_kernel(ProjArgs a) {
  __shared__ __align__(16) unsigned char smem[16384];
  const int z = blockIdx.z;
  proj_body(smem, a.X[z], a.W[z], a.bias[z], a.outb[z], a.outf, a.mode[z],
            blockIdx.x, blockIdx.y);
}

// ---------------- flash attention ----------------
// grid 1024 (XCD-swizzled): 32 qt x 32 bh; 4 waves; wave owns 16 Q rows.
// K/V double-buffered in LDS (1 barrier/tile); V pre-transposed in global.
// All LDS tiles are 64x128B rows, content XOR-swizzled: byte ^= (row&7)<<4.
__global__ __launch_bounds__(256, 4) void attn_kernel(
    const unsigned short* __restrict__ Qh, const unsigned short* __restrict__ Kh,
    const unsigned short* __restrict__ Vt, unsigned short* __restrict__ AO) {
  __shared__ __align__(16) unsigned char smem[40960];
  const int tid = threadIdx.x, wid = tid >> 6, lane = tid & 63;
  const int l15 = lane & 15, l4 = lane >> 4;
  const int bid = blockIdx.x;
  const int swz = (bid & 7) * 128 + (bid >> 3);  // bijective: 1024 % 8 == 0
  const int qt = swz & 31, bh = swz >> 5;

  const unsigned short* Qb = Qh + ((size_t)bh * SEQ + qt * 64) * HD;
  const unsigned short* Kb = Kh + (size_t)bh * SEQ * HD;
  const unsigned short* Vb = Vt + (size_t)bh * HD * SEQ;
  unsigned char* P = smem + 32768 + wid * 2048;  // per-wave P, XOR-swizzled rows

  // prologue: Q tile -> buf1 K region; K/V tile 0 -> buf0. (pre-swizzled src)
#pragma unroll
  for (int is = 0; is < 2; ++is) {
    const int p = wid * 2048 + is * 1024 + lane * 16;
    const int row = p >> 7;
    const int sw = ((p & 127) ^ ((row & 7) << 4)) >> 1;  // elem offset in row
    gload16(Qb + row * HD + sw, smem + 16384 + wid * 2048 + is * 1024);
    gload16(Kb + (size_t)row * HD + sw, smem + wid * 2048 + is * 1024);
    gload16(Vb + (size_t)row * SEQ + sw, smem + 8192 + wid * 2048 + is * 1024);
  }
  __syncthreads();

  bf16x8 qf[2];
#pragma unroll
  for (int kk = 0; kk < 2; ++kk) {
    const int row = wid * 16 + l15;
    qf[kk] = *(const bf16x8*)(smem + 16384 + row * 128 +
                              ((kk * 64 + l4 * 16) ^ ((row & 7) << 4)));
  }

  f32x4 O[4] = {};
  float mrow[4], lrow[4];
#pragma unroll
  for (int r = 0; r < 4; ++r) { mrow[r] = -1e30f; lrow[r] = 0.f; }

  int cur = 0;
  for (int it = 0; it < 32; ++it) {
    // barrier: buf[cur] staged (vmcnt drained), all waves done with buf[cur^1]
    // (and at it==0: all waves done reading qf from buf1's K region)
    __syncthreads();
    if (it + 1 < 32) {
      const int j0 = (it + 1) * 64;
      unsigned char* D = smem + (cur ^ 1) * 16384;
#pragma unroll
      for (int is = 0; is < 2; ++is) {
        const int p = wid * 2048 + is * 1024 + lane * 16;
        const int row = p >> 7;
        const int sw = ((p & 127) ^ ((row & 7) << 4)) >> 1;
        gload16(Kb + (size_t)(j0 + row) * HD + sw, D + wid * 2048 + is * 1024);
        gload16(Vb + (size_t)row * SEQ + j0 + sw, D + 8192 + wid * 2048 + is * 1024);
      }
    }
    unsigned char* Kc = smem + cur * 16384;
    unsigned char* Vc = Kc + 8192;

    // S = Q @ K^T (log2-domain: Q pre-scaled by d^-1/2 * log2e)
    f32x4 S[4] = {};
#pragma unroll
    for (int kk = 0; kk < 2; ++kk) {
#pragma unroll
      for (int nj = 0; nj < 4; ++nj) {
        const int kr = nj * 16 + l15;
        const bf16x8 kf = *(const bf16x8*)(Kc + kr * 128 +
                                           ((kk * 64 + l4 * 16) ^ ((kr & 7) << 4)));
#pragma unroll
        for (int mi = 0; mi < 1; ++mi)
          S[nj] = __builtin_amdgcn_mfma_f32_16x16x32_bf16(qf[kk], kf, S[nj], 0, 0, 0);
      }
    }

    // online softmax, base-2 domain; row q = l4*4+r, cols over l15 x nj
#pragma unroll
    for (int r = 0; r < 4; ++r) {
      float nm = fmaxf(fmaxf(S[0][r], S[1][r]), fmaxf(S[2][r], S[3][r]));
      nm = fmaxf(nm, __shfl_xor(nm, 1));
      nm = fmaxf(nm, __shfl_xor(nm, 2));
      nm = fmaxf(nm, __shfl_xor(nm, 4));
      nm = fmaxf(nm, __shfl_xor(nm, 8));
      const float mnew = fmaxf(mrow[r], nm);
      const float alpha = exp2f(mrow[r] - mnew);
      mrow[r] = mnew;
      float rs = 0.f;
#pragma unroll
      for (int nj = 0; nj < 4; ++nj) {
        const float pv = exp2f(S[nj][r] - mnew);
        S[nj][r] = pv;
        rs += pv;
      }
      rs += __shfl_xor(rs, 1);
      rs += __shfl_xor(rs, 2);
      rs += __shfl_xor(rs, 4);
      rs += __shfl_xor(rs, 8);
      lrow[r] = lrow[r] * alpha + rs;
#pragma unroll
      for (int nf = 0; nf < 4; ++nf) O[nf][r] *= alpha;
    }

    // P -> per-wave LDS (XOR-swizzled rows); same-wave read, no barrier
#pragma unroll
    for (int r = 0; r < 4; ++r) {
      const int row = l4 * 4 + r;
      const int sx = (row & 7) << 4;
#pragma unroll
      for (int nj = 0; nj < 4; ++nj)
        *(unsigned short*)(P + row * 128 + (((nj * 16 + l15) * 2) ^ sx)) = f2b(S[nj][r]);
    }

    // O += P @ V
#pragma unroll
    for (int kk = 0; kk < 2; ++kk) {
      const bf16x8 pa = *(const bf16x8*)(P + l15 * 128 +
                                         ((kk * 64 + l4 * 16) ^ ((l15 & 7) << 4)));
#pragma unroll
      for (int nf = 0; nf < 4; ++nf) {
        const int vr = nf * 16 + l15;
        const bf16x8 vf = *(const bf16x8*)(Vc + vr * 128 +
                                           ((kk * 64 + l4 * 16) ^ ((vr & 7) << 4)));
        O[nf] = __builtin_amdgcn_mfma_f32_16x16x32_bf16(pa, vf, O[nf], 0, 0, 0);
      }
    }
    cur ^= 1;
  }

  // epilogue
  const int b = bh >> 4, h = bh & 15;
#pragma unroll
  for (int nf = 0; nf < 4; ++nf) {
    const int d = nf * 16 + l15;
#pragma unroll
    for (int r = 0; r < 4; ++r) {
      const int n = qt * 64 + wid * 16 + l4 * 4 + r;
      AO[((size_t)(b * SEQ + n)) * CH + h * HD + d] = f2b(O[nf][r] / lrow[r]);
    }
  }
}

extern "C" void kernel_launch(void* const* d_in, const int* in_sizes, int n_in,
                              void* d_out, int out_size, void* d_ws, size_t ws_size,
                              hipStream_t stream) {
  (void)in_sizes; (void)n_in; (void)out_size; (void)ws_size;
  const float* q  = (const float*)d_in[0];
  const float* k  = (const float*)d_in[1];
  const float* v  = (const float*)d_in[2];
  const float* wq = (const float*)d_in[3];
  const float* bq = (const float*)d_in[4];
  const float* wk = (const float*)d_in[5];
  const float* bk = (const float*)d_in[6];
  const float* wv = (const float*)d_in[7];
  const float* bv = (const float*)d_in[8];
  const float* wo = (const float*)d_in[9];
  const float* bo = (const float*)d_in[10];

  unsigned char* ws = (unsigned char*)d_ws;
  const size_t MB8 = 8u << 20;
  unsigned short* qb  = (unsigned short*)(ws + 0 * MB8);
  unsigned short* kb  = (unsigned short*)(ws + 1 * MB8);
  unsigned short* vb  = (unsigned short*)(ws + 2 * MB8);
  unsigned short* wqb = (unsigned short*)(ws + 3 * MB8);
  unsigned short* wkb = (unsigned short*)(ws + 3 * MB8 + 1 * 2097152);
  unsigned short* wvb = (unsigned short*)(ws + 3 * MB8 + 2 * 2097152);
  unsigned short* wob = (unsigned short*)(ws + 3 * MB8 + 3 * 2097152);
  unsigned short* Qh  = (unsigned short*)(ws + 4 * MB8);
  unsigned short* Kh  = (unsigned short*)(ws + 5 * MB8);
  unsigned short* VtT = kb;  // kb dead after QK proj (V proj launched after)
  unsigned short* AO  = qb;  // qb dead after QK proj
  float* out = (float*)d_out;

  CvtArgs ca;
  ca.src[0] = q;  ca.dst[0] = qb;  ca.n4[0] = TOK * CH / 4;
  ca.src[1] = k;  ca.dst[1] = kb;  ca.n4[1] = TOK * CH / 4;
  ca.src[2] = v;  ca.dst[2] = vb;  ca.n4[2] = TOK * CH / 4;
  ca.src[3] = wq; ca.dst[3] = wqb; ca.n4[3] = CH * CH / 4;
  ca.src[4] = wk; ca.dst[4] = wkb; ca.n4[4] = CH * CH / 4;
  ca.src[5] = wv; ca.dst[5] = wvb; ca.n4[5] = CH * CH / 4;
  ca.src[6] = wo; ca.dst[6] = wob; ca.n4[6] = CH * CH / 4;
  cvt_kernel<<<dim3(1024, 7), 256, 0, stream>>>(ca);

  ProjArgs qk;
  qk.X[0] = qb;  qk.W[0] = wqb; qk.bias[0] = bq; qk.outb[0] = Qh; qk.mode[0] = 0;
  qk.X[1] = kb;  qk.W[1] = wkb; qk.bias[1] = bk; qk.outb[1] = Kh; qk.mode[1] = 1;
  qk.outf = nullptr;
  proj_kernel<<<dim3(32, 8, 2), 256, 0, stream>>>(qk);

  ProjArgs vp;
  vp.X[0] = vb;  vp.W[0] = wvb; vp.bias[0] = bv; vp.outb[0] = VtT; vp.mode[0] = 3;
  vp.X[1] = vb;  vp.W[1] = wvb; vp.bias[1] = bv; vp.outb[1] = VtT; vp.mode[1] = 3;
  vp.outf = nullptr;
  proj_kernel<<<dim3(32, 8, 1), 256, 0, stream>>>(vp);

  attn_kernel<<<dim3(1024), 256, 0, stream>>>(Qh, Kh, VtT, AO);

  ProjArgs op;
  op.X[0] = AO; op.W[0] = wob; op.bias[0] = bo; op.outb[0] = nullptr; op.mode[0] = 2;
  op.X[1] = AO; op.W[1] = wob; op.bias[1] = bo; op.outb[1] = nullptr; op.mode[1] = 2;
  op.outf = out;
  proj_kernel<<<dim3(32, 8, 1), 256, 0, stream>>>(op);
}

// Round 4
// 162.226 us; speedup vs baseline: 1.8047x; 1.3006x over previous
//
#include <hip/hip_runtime.h>

// MHA b=2 n=2048 c=1024 h=16 d=64. bf16 MFMA everywhere, f32 accum.
// ws (48MB): qb(8M) kb(8M) vb(8M) w*(4x2M) Qh(8M) Kh(8M); Vt=kb, AO=qb.

typedef float f32x4 __attribute__((ext_vector_type(4)));
typedef float f32x16 __attribute__((ext_vector_type(16)));
typedef __bf16 bf16x8 __attribute__((ext_vector_type(8)));

#define SEQ 2048
#define CH 1024
#define NH 16
#define HD 64
#define TOK 4096
// 0.125 (d^-1/2) * log2(e): fold softmax base-2 conversion into Q
#define QSCALE 0.18033688011112042f

__device__ __forceinline__ unsigned short f2b(float f) {
  unsigned int u = __float_as_uint(f);
  u = (u + 0x7FFFu + ((u >> 16) & 1u)) >> 16;  // RNE
  return (unsigned short)u;
}

__device__ __forceinline__ unsigned int cvtpk(float lo, float hi) {
  unsigned int r;
  asm("v_cvt_pk_bf16_f32 %0, %1, %2" : "=v"(r) : "v"(lo), "v"(hi));
  return r;
}

__device__ __forceinline__ void gload16(const void* g, void* l) {
  __builtin_amdgcn_global_load_lds(
      (const __attribute__((address_space(1))) unsigned int*)g,
      (__attribute__((address_space(3))) unsigned int*)l, 16, 0, 0);
}

// ---------------- f32 -> bf16 conversion ----------------
struct CvtArgs {
  const float* src[7];
  unsigned short* dst[7];
  int n4[7];
};

__global__ __launch_bounds__(256) void cvt_kernel(CvtArgs a) {
  const int s = blockIdx.y;
  const int n4 = a.n4[s];
  const float4* __restrict__ src = (const float4*)a.src[s];
  unsigned short* __restrict__ dst = a.dst[s];
  const int stride = gridDim.x * blockDim.x;
  for (int i = blockIdx.x * blockDim.x + threadIdx.x; i < n4; i += stride) {
    float4 w = src[i];
    ushort4 o;
    o.x = f2b(w.x); o.y = f2b(w.y); o.z = f2b(w.z); o.w = f2b(w.w);
    *(ushort4*)(dst + 4 * (size_t)i) = o;
  }
}

// ---------------- GEMM: X[4096,1024] @ W^T + bias ----------------
// mode 0: bf16 head layout [bh][n][d], scaled by QSCALE (Q)
// mode 1: bf16 head layout (K)
// mode 2: f32 flat [4096][1024] (output projection)
// mode 3: bf16 transposed head layout [bh][d][n] (V^T)
__device__ __forceinline__ void proj_body(
    unsigned char* smem, const unsigned short* __restrict__ X,
    const unsigned short* __restrict__ W, const float* __restrict__ bias,
    unsigned short* __restrict__ outb, float* __restrict__ outf,
    const int mode, const int mt, const int nt) {
  unsigned char* Al = smem;
  unsigned char* Bl = smem + 8192;
  const int tid = threadIdx.x;
  const int wid = tid >> 6, lane = tid & 63;
  const int wm = wid >> 1, wn = wid & 1;
  const int l15 = lane & 15, l4 = lane >> 4;

  f32x4 acc[4][4] = {};

  for (int k0 = 0; k0 < CH; k0 += 32) {
#pragma unroll
    for (int is = 0; is < 2; ++is) {
      const int p = (wid * 2 + is) * 1024 + lane * 16;
      const int row = p >> 6;
      const int cole = (p & 63) >> 1;
      gload16(X + (size_t)(mt * 128 + row) * CH + k0 + cole, Al + (wid * 2 + is) * 1024);
      gload16(W + (size_t)(nt * 128 + row) * CH + k0 + cole, Bl + (wid * 2 + is) * 1024);
    }
    __syncthreads();
    bf16x8 af[4], bfr[4];
#pragma unroll
    for (int mi = 0; mi < 4; ++mi)
      af[mi] = *(const bf16x8*)(Al + (wm * 64 + mi * 16 + l15) * 64 + l4 * 16);
#pragma unroll
    for (int nj = 0; nj < 4; ++nj)
      bfr[nj] = *(const bf16x8*)(Bl + (wn * 64 + nj * 16 + l15) * 64 + l4 * 16);
#pragma unroll
    for (int mi = 0; mi < 4; ++mi)
#pragma unroll
      for (int nj = 0; nj < 4; ++nj)
        acc[mi][nj] = __builtin_amdgcn_mfma_f32_16x16x32_bf16(af[mi], bfr[nj], acc[mi][nj], 0, 0, 0);
    __syncthreads();
  }

  const int row0 = mt * 128 + wm * 64;
  const int col0 = nt * 128 + wn * 64;
#pragma unroll
  for (int nj = 0; nj < 4; ++nj) {
    const int col = col0 + nj * 16 + l15;
    const float bv = bias[col];
    const int h = col >> 6, d = col & 63;
    if (mode == 3) {
      // V^T: pack 4 consecutive n per (mi,nj)
#pragma unroll
      for (int mi = 0; mi < 4; ++mi) {
        const int row = row0 + mi * 16 + l4 * 4;
        const int b = row >> 11, n = row & (SEQ - 1);
        ushort4 o;
        o.x = f2b(acc[mi][nj][0] + bv);
        o.y = f2b(acc[mi][nj][1] + bv);
        o.z = f2b(acc[mi][nj][2] + bv);
        o.w = f2b(acc[mi][nj][3] + bv);
        *(ushort4*)(outb + ((size_t)(b * NH + h) * HD + d) * SEQ + n) = o;
      }
    } else {
#pragma unroll
      for (int mi = 0; mi < 4; ++mi) {
#pragma unroll
        for (int r = 0; r < 4; ++r) {
          const int row = row0 + mi * 16 + l4 * 4 + r;
          float v = acc[mi][nj][r] + bv;
          if (mode == 0) v *= QSCALE;
          if (mode == 2) {
            outf[(size_t)row * CH + col] = v;
          } else {
            const int b = row >> 11, n = row & (SEQ - 1);
            outb[(((size_t)(b * NH + h) * SEQ + n) << 6) + d] = f2b(v);
          }
        }
      }
    }
  }
}

struct ProjArgs {
  const unsigned short* X[2];
  const unsigned short* W[2];
  const float* bias[2];
  unsigned short* outb[2];
  float* outf;
  int mode[2];
};

__global__ __launch_bounds__(256) void proj_kernel(ProjArgs a) {
  __shared__ __align__(16) unsigned char smem[16384];
  const int z = blockIdx.z;
  proj_body(smem, a.X[z], a.W[z], a.bias[z], a.outb[z], a.outf, a.mode[z],
            blockIdx.x, blockIdx.y);
}

// ---------------- flash attention (swapped-operand 32x32 MFMA) ----------------
// grid 512 (XCD-swizzled): 16 qt x 32 bh; 4 waves x 32 q rows = 128 q/block.
// S^T = mfma_32x32x16(K, Q): lane owns q = lane&31 -> in-register softmax.
// P -> PV A-frags via cvt_pk + shfl_xor(32) + cndmask (no LDS round trip).
// K/V double-buffered LDS; rows 128B, content XOR-swizzled byte^=(row&7)<<4.
__global__ __launch_bounds__(256, 2) void attn_kernel(
    const unsigned short* __restrict__ Qh, const unsigned short* __restrict__ Kh,
    const unsigned short* __restrict__ Vt, unsigned short* __restrict__ AO) {
  __shared__ __align__(16) unsigned char smem[32768];
  const int tid = threadIdx.x, wid = tid >> 6, lane = tid & 63;
  const int l31 = lane & 31, h = lane >> 5;
  const int bid = blockIdx.x;
  const int swz = (bid & 7) * 64 + (bid >> 3);  // bijective: 512 % 8 == 0
  const int qt = swz & 15, bh = swz >> 4;

  const unsigned short* Qb = Qh + ((size_t)bh * SEQ + qt * 128) * HD;
  const unsigned short* Kb = Kh + (size_t)bh * SEQ * HD;
  const unsigned short* Vb = Vt + (size_t)bh * HD * SEQ;

  // ---- stage Q tile (128 rows x 128B, swizzled) into smem[0..16K) ----
#pragma unroll
  for (int is = 0; is < 4; ++is) {
    const int p = wid * 4096 + is * 1024 + lane * 16;
    const int row = p >> 7;
    const int sw = ((p & 127) ^ ((row & 7) << 4)) >> 1;
    gload16(Qb + (size_t)row * HD + sw, smem + wid * 4096 + is * 1024);
  }
  __syncthreads();

  // Q B-fragments: B[k=16ks+8h+e][q=l31] = Q[q][d]; row q, bytes 32ks+16h
  bf16x8 qf[4];
  const int qrow = wid * 32 + l31;
#pragma unroll
  for (int ks = 0; ks < 4; ++ks)
    qf[ks] = *(const bf16x8*)(smem + qrow * 128 + ((ks * 32 + h * 16) ^ ((qrow & 7) << 4)));
  __syncthreads();  // all waves done reading Q; smem reusable

  // ---- stage K/V tile 0 into buf0 ----
#pragma unroll
  for (int is = 0; is < 2; ++is) {
    const int p = wid * 2048 + is * 1024 + lane * 16;
    const int row = p >> 7;
    const int sw = ((p & 127) ^ ((row & 7) << 4)) >> 1;
    gload16(Kb + (size_t)row * HD + sw, smem + wid * 2048 + is * 1024);
    gload16(Vb + (size_t)row * SEQ + sw, smem + 8192 + wid * 2048 + is * 1024);
  }

  f32x16 O[2] = {};
  float m = -1e30f, l = 0.f;

  int cur = 0;
  for (int it = 0; it < 32; ++it) {
    __syncthreads();  // buf[cur] staged (barrier drains vmcnt); prev compute done
    if (it + 1 < 32) {
      const int j0 = (it + 1) * 64;
      unsigned char* D = smem + (cur ^ 1) * 16384;
#pragma unroll
      for (int is = 0; is < 2; ++is) {
        const int p = wid * 2048 + is * 1024 + lane * 16;
        const int row = p >> 7;
        const int sw = ((p & 127) ^ ((row & 7) << 4)) >> 1;
        gload16(Kb + (size_t)(j0 + row) * HD + sw, D + wid * 2048 + is * 1024);
        gload16(Vb + (size_t)row * SEQ + j0 + sw, D + 8192 + wid * 2048 + is * 1024);
      }
    }
    unsigned char* Kc = smem + cur * 16384;
    unsigned char* Vc = Kc + 8192;

    // ---- S^T = K @ Q^T : st[kb] covers keys 32kb..32kb+31 for q=l31 ----
    // lane holds key = 32kb + (r&3)+8*(r>>2)+4h, r=0..15
    f32x16 st[2] = {};
#pragma unroll
    for (int kb = 0; kb < 2; ++kb) {
#pragma unroll
      for (int ks = 0; ks < 4; ++ks) {
        const int krow = kb * 32 + l31;
        const bf16x8 kf = *(const bf16x8*)(Kc + krow * 128 +
                                           ((ks * 32 + h * 16) ^ ((krow & 7) << 4)));
        st[kb] = __builtin_amdgcn_mfma_f32_32x32x16_bf16(kf, qf[ks], st[kb], 0, 0, 0);
      }
    }

    // ---- in-register online softmax (base-2 domain), defer-max THR=8 ----
    float t[8];
#pragma unroll
    for (int i = 0; i < 8; ++i)
      t[i] = fmaxf(fmaxf(st[0][i], st[0][i + 8]), fmaxf(st[1][i], st[1][i + 8]));
#pragma unroll
    for (int i = 0; i < 4; ++i) t[i] = fmaxf(t[i], t[i + 4]);
    float pmax = fmaxf(fmaxf(t[0], t[1]), fmaxf(t[2], t[3]));
    pmax = fmaxf(pmax, __shfl_xor(pmax, 32));
    if (__any(pmax > m + 8.f)) {
      const float mnew = fmaxf(m, pmax);
      const float alpha = exp2f(m - mnew);
#pragma unroll
      for (int r = 0; r < 16; ++r) {
        const int qO = (r & 3) + 8 * (r >> 2) + 4 * h;
        const float aO = __shfl(alpha, qO);
        O[0][r] *= aO;
        O[1][r] *= aO;
      }
      l *= alpha;
      m = mnew;
    }
#pragma unroll
    for (int kb = 0; kb < 2; ++kb)
#pragma unroll
      for (int i = 0; i < 16; ++i) st[kb][i] = exp2f(st[kb][i] - m);
    float s[8];
#pragma unroll
    for (int i = 0; i < 8; ++i)
      s[i] = (st[0][i] + st[0][i + 8]) + (st[1][i] + st[1][i + 8]);
#pragma unroll
    for (int i = 0; i < 4; ++i) s[i] += s[i + 4];
    float rs = (s[0] + s[1]) + (s[2] + s[3]);
    rs += __shfl_xor(rs, 32);
    l += rs;

    // ---- pack P to bf16 pairs ----
    // pk[kb][j] = keys {base+4h, base+4h+1}: j=0..7 -> base = 8*(j>>1)+2*(j&1)
    unsigned int pk[2][8];
#pragma unroll
    for (int kb = 0; kb < 2; ++kb)
#pragma unroll
      for (int j = 0; j < 8; ++j)
        pk[kb][j] = cvtpk(st[kb][2 * j], st[kb][2 * j + 1]);

    // ---- build PV A-frags: lane needs P[q=l31][16kk + 8h + e] ----
    // h=0 wants {own j0, own j0+1, partner(h=1) j0, partner j0+1}
    // h=1 wants {partner(h=0) j0+2, partner j0+3, own j0+2, own j0+3}
#pragma unroll
    for (int kk = 0; kk < 4; ++kk) {
      const int kb = kk >> 1, j0 = (kk & 1) * 4;
      const unsigned int p0 = pk[kb][j0 + 0], p1 = pk[kb][j0 + 1];
      const unsigned int p2 = pk[kb][j0 + 2], p3 = pk[kb][j0 + 3];
      const unsigned int u0 = h ? p0 : p2;
      const unsigned int u1 = h ? p1 : p3;
      const unsigned int su0 = __shfl_xor(u0, 32);
      const unsigned int su1 = __shfl_xor(u1, 32);
      const unsigned int d0 = h ? su0 : p0;
      const unsigned int d1 = h ? su1 : p1;
      const unsigned int d2 = h ? p2 : su0;
      const unsigned int d3 = h ? p3 : su1;
      uint4 aw = make_uint4(d0, d1, d2, d3);
      const bf16x8 af = *(const bf16x8*)&aw;
#pragma unroll
      for (int db = 0; db < 2; ++db) {
        const int vrow = db * 32 + l31;
        const bf16x8 vf = *(const bf16x8*)(Vc + vrow * 128 +
                                           ((kk * 32 + h * 16) ^ ((vrow & 7) << 4)));
        O[db] = __builtin_amdgcn_mfma_f32_32x32x16_bf16(af, vf, O[db], 0, 0, 0);
      }
    }
    cur ^= 1;
  }

  // ---- epilogue: O/l, write bf16 to [b][n][head*64+d] ----
  const int b = bh >> 4, hh = bh & 15;
#pragma unroll
  for (int r = 0; r < 16; ++r) {
    const int qO = (r & 3) + 8 * (r >> 2) + 4 * h;
    const float lO = __shfl(l, qO);
    const float inv = 1.f / lO;
    const int n = qt * 128 + wid * 32 + qO;
    const size_t base = ((size_t)(b * SEQ + n)) * CH + hh * HD;
    AO[base + l31] = f2b(O[0][r] * inv);
    AO[base + 32 + l31] = f2b(O[1][r] * inv);
  }
}

extern "C" void kernel_launch(void* const* d_in, const int* in_sizes, int n_in,
                              void* d_out, int out_size, void* d_ws, size_t ws_size,
                              hipStream_t stream) {
  (void)in_sizes; (void)n_in; (void)out_size; (void)ws_size;
  const float* q  = (const float*)d_in[0];
  const float* k  = (const float*)d_in[1];
  const float* v  = (const float*)d_in[2];
  const float* wq = (const float*)d_in[3];
  const float* bq = (const float*)d_in[4];
  const float* wk = (const float*)d_in[5];
  const float* bk = (const float*)d_in[6];
  const float* wv = (const float*)d_in[7];
  const float* bv = (const float*)d_in[8];
  const float* wo = (const float*)d_in[9];
  const float* bo = (const float*)d_in[10];

  unsigned char* ws = (unsigned char*)d_ws;
  const size_t MB8 = 8u << 20;
  unsigned short* qb  = (unsigned short*)(ws + 0 * MB8);
  unsigned short* kb  = (unsigned short*)(ws + 1 * MB8);
  unsigned short* vb  = (unsigned short*)(ws + 2 * MB8);
  unsigned short* wqb = (unsigned short*)(ws + 3 * MB8);
  unsigned short* wkb = (unsigned short*)(ws + 3 * MB8 + 1 * 2097152);
  unsigned short* wvb = (unsigned short*)(ws + 3 * MB8 + 2 * 2097152);
  unsigned short* wob = (unsigned short*)(ws + 3 * MB8 + 3 * 2097152);
  unsigned short* Qh  = (unsigned short*)(ws + 4 * MB8);
  unsigned short* Kh  = (unsigned short*)(ws + 5 * MB8);
  unsigned short* VtT = kb;  // kb dead after QK proj (V proj launched after)
  unsigned short* AO  = qb;  // qb dead after QK proj
  float* out = (float*)d_out;

  CvtArgs ca;
  ca.src[0] = q;  ca.dst[0] = qb;  ca.n4[0] = TOK * CH / 4;
  ca.src[1] = k;  ca.dst[1] = kb;  ca.n4[1] = TOK * CH / 4;
  ca.src[2] = v;  ca.dst[2] = vb;  ca.n4[2] = TOK * CH / 4;
  ca.src[3] = wq; ca.dst[3] = wqb; ca.n4[3] = CH * CH / 4;
  ca.src[4] = wk; ca.dst[4] = wkb; ca.n4[4] = CH * CH / 4;
  ca.src[5] = wv; ca.dst[5] = wvb; ca.n4[5] = CH * CH / 4;
  ca.src[6] = wo; ca.dst[6] = wob; ca.n4[6] = CH * CH / 4;
  cvt_kernel<<<dim3(1024, 7), 256, 0, stream>>>(ca);

  ProjArgs qk;
  qk.X[0] = qb;  qk.W[0] = wqb; qk.bias[0] = bq; qk.outb[0] = Qh; qk.mode[0] = 0;
  qk.X[1] = kb;  qk.W[1] = wkb; qk.bias[1] = bk; qk.outb[1] = Kh; qk.mode[1] = 1;
  qk.outf = nullptr;
  proj_kernel<<<dim3(32, 8, 2), 256, 0, stream>>>(qk);

  ProjArgs vp;
  vp.X[0] = vb;  vp.W[0] = wvb; vp.bias[0] = bv; vp.outb[0] = VtT; vp.mode[0] = 3;
  vp.X[1] = vb;  vp.W[1] = wvb; vp.bias[1] = bv; vp.outb[1] = VtT; vp.mode[1] = 3;
  vp.outf = nullptr;
  proj_kernel<<<dim3(32, 8, 1), 256, 0, stream>>>(vp);

  attn_kernel<<<dim3(512), 256, 0, stream>>>(Qh, Kh, VtT, AO);

  ProjArgs op;
  op.X[0] = AO; op.W[0] = wob; op.bias[0] = bo; op.outb[0] = nullptr; op.mode[0] = 2;
  op.X[1] = AO; op.W[1] = wob; op.bias[1] = bo; op.outb[1] = nullptr; op.mode[1] = 2;
  op.outf = out;
  proj_kernel<<<dim3(32, 8, 1), 256, 0, stream>>>(op);
}

// Round 5
// 149.621 us; speedup vs baseline: 1.9568x; 1.0842x over previous
//
#include <hip/hip_runtime.h>

// MHA b=2 n=2048 c=1024 h=16 d=64. bf16 MFMA everywhere, f32 accum.
// ws (48MB): qb(8M) kb(8M) vb(8M) w*(4x2M) Qh(8M) Kh(8M); Vt=kb, AO=qb.
// R5: counted-vmcnt 3-buffer pipelines (T4) in attn+proj, setprio (T5),
//     TN=64 proj tiles for occupancy (QK fused launch = 1024 blocks).

typedef float f32x4 __attribute__((ext_vector_type(4)));
typedef float f32x16 __attribute__((ext_vector_type(16)));
typedef __bf16 bf16x8 __attribute__((ext_vector_type(8)));

#define SEQ 2048
#define CH 1024
#define NH 16
#define HD 64
#define TOK 4096
// 0.125 (d^-1/2) * log2(e): fold softmax base-2 conversion into Q
#define QSCALE 0.18033688011112042f

__device__ __forceinline__ unsigned short f2b(float f) {
  unsigned int u = __float_as_uint(f);
  u = (u + 0x7FFFu + ((u >> 16) & 1u)) >> 16;  // RNE
  return (unsigned short)u;
}

__device__ __forceinline__ unsigned int cvtpk(float lo, float hi) {
  unsigned int r;
  asm("v_cvt_pk_bf16_f32 %0, %1, %2" : "=v"(r) : "v"(lo), "v"(hi));
  return r;
}

__device__ __forceinline__ void gload16(const void* g, void* l) {
  __builtin_amdgcn_global_load_lds(
      (const __attribute__((address_space(1))) unsigned int*)g,
      (__attribute__((address_space(3))) unsigned int*)l, 16, 0, 0);
}

// ---------------- f32 -> bf16 conversion ----------------
struct CvtArgs {
  const float* src[7];
  unsigned short* dst[7];
  int n4[7];
};

__global__ __launch_bounds__(256) void cvt_kernel(CvtArgs a) {
  const int s = blockIdx.y;
  const int n4 = a.n4[s];
  const float4* __restrict__ src = (const float4*)a.src[s];
  unsigned short* __restrict__ dst = a.dst[s];
  const int stride = gridDim.x * blockDim.x;
  for (int i = blockIdx.x * blockDim.x + threadIdx.x; i < n4; i += stride) {
    float4 w = src[i];
    ushort4 o;
    o.x = f2b(w.x); o.y = f2b(w.y); o.z = f2b(w.z); o.w = f2b(w.w);
    *(ushort4*)(dst + 4 * (size_t)i) = o;
  }
}

// ---------------- GEMM: X[4096,1024] @ W^T + bias, 128x64 tile ----------------
// mode 0: bf16 head layout [bh][n][d], scaled by QSCALE (Q)
// mode 1: bf16 head layout (K)
// mode 2: f32 flat [4096][1024] (output projection)
// mode 3: bf16 transposed head layout [bh][d][n] (V^T)
struct ProjArgs {
  const unsigned short* X[2];
  const unsigned short* W[2];
  const float* bias[2];
  unsigned short* outb[2];
  float* outf;
  int mode[2];
};

// stage one K-step (BK=32): A 128x32 (8KB) + B 64x32 (4KB); 3 gload16/lane
__device__ __forceinline__ void proj_stage(
    const unsigned short* __restrict__ X, const unsigned short* __restrict__ W,
    int mt, int nt, int k0, unsigned char* buf, int wid, int lane) {
#pragma unroll
  for (int is = 0; is < 2; ++is) {
    const int p = (wid * 2 + is) * 1024 + lane * 16;
    gload16(X + (size_t)(mt * 128 + (p >> 6)) * CH + k0 + ((p & 63) >> 1),
            buf + (wid * 2 + is) * 1024);
  }
  {
    const int p = wid * 1024 + lane * 16;
    gload16(W + (size_t)(nt * 64 + (p >> 6)) * CH + k0 + ((p & 63) >> 1),
            buf + 8192 + wid * 1024);
  }
}

__global__ __launch_bounds__(256, 4) void proj_kernel(ProjArgs a) {
  constexpr int BUFB = 8192 + 4096;  // A + B bytes per buffer
  __shared__ __align__(16) unsigned char smem[3 * BUFB];
  const int z = blockIdx.z;
  const unsigned short* __restrict__ X = a.X[z];
  const unsigned short* __restrict__ W = a.W[z];
  const float* __restrict__ bias = a.bias[z];
  unsigned short* __restrict__ outb = a.outb[z];
  float* __restrict__ outf = a.outf;
  const int mode = a.mode[z];
  const int tid = threadIdx.x, wid = tid >> 6, lane = tid & 63;
  const int wm = wid >> 1, wn = wid & 1;
  const int mt = blockIdx.x, nt = blockIdx.y;
  const int l15 = lane & 15, l4 = lane >> 4;

  // bias loads pinned BEFORE stage(0): they retire early and never perturb
  // the in-loop vmcnt counting (they are oldest if still outstanding).
  float bvv[2];
#pragma unroll
  for (int nj = 0; nj < 2; ++nj)
    bvv[nj] = bias[nt * 64 + wn * 32 + nj * 16 + l15];

  f32x4 acc[4][2] = {};

  proj_stage(X, W, mt, nt, 0, smem, wid, lane);
  proj_stage(X, W, mt, nt, 32, smem + BUFB, wid, lane);

  for (int s = 0; s < 32; ++s) {
    // tile s done (its 3 loads are this wave's oldest); keep s+1 in flight
    if (s < 31) asm volatile("s_waitcnt vmcnt(3)" ::: "memory");
    else        asm volatile("s_waitcnt vmcnt(0)" ::: "memory");
    __builtin_amdgcn_s_barrier();
    __builtin_amdgcn_sched_barrier(0);
    if (s + 2 < 32)
      proj_stage(X, W, mt, nt, (s + 2) * 32, smem + ((s + 2) % 3) * BUFB, wid, lane);

    unsigned char* Al = smem + (s % 3) * BUFB;
    unsigned char* Bl = Al + 8192;
    bf16x8 af[4], bfr[2];
#pragma unroll
    for (int mi = 0; mi < 4; ++mi)
      af[mi] = *(const bf16x8*)(Al + (wm * 64 + mi * 16 + l15) * 64 + l4 * 16);
#pragma unroll
    for (int nj = 0; nj < 2; ++nj)
      bfr[nj] = *(const bf16x8*)(Bl + (wn * 32 + nj * 16 + l15) * 64 + l4 * 16);
    __builtin_amdgcn_s_setprio(1);
#pragma unroll
    for (int mi = 0; mi < 4; ++mi)
#pragma unroll
      for (int nj = 0; nj < 2; ++nj)
        acc[mi][nj] = __builtin_amdgcn_mfma_f32_16x16x32_bf16(af[mi], bfr[nj], acc[mi][nj], 0, 0, 0);
    __builtin_amdgcn_s_setprio(0);
  }

  const int row0 = mt * 128 + wm * 64;
  const int col0 = nt * 64 + wn * 32;
#pragma unroll
  for (int nj = 0; nj < 2; ++nj) {
    const int col = col0 + nj * 16 + l15;
    const float bv = bvv[nj];
    const int h = col >> 6, d = col & 63;
    if (mode == 3) {
      // V^T: pack 4 consecutive n per (mi,nj)
#pragma unroll
      for (int mi = 0; mi < 4; ++mi) {
        const int row = row0 + mi * 16 + l4 * 4;
        const int b = row >> 11, n = row & (SEQ - 1);
        ushort4 o;
        o.x = f2b(acc[mi][nj][0] + bv);
        o.y = f2b(acc[mi][nj][1] + bv);
        o.z = f2b(acc[mi][nj][2] + bv);
        o.w = f2b(acc[mi][nj][3] + bv);
        *(ushort4*)(outb + ((size_t)(b * NH + h) * HD + d) * SEQ + n) = o;
      }
    } else {
#pragma unroll
      for (int mi = 0; mi < 4; ++mi) {
#pragma unroll
        for (int r = 0; r < 4; ++r) {
          const int row = row0 + mi * 16 + l4 * 4 + r;
          float v = acc[mi][nj][r] + bv;
          if (mode == 0) v *= QSCALE;
          if (mode == 2) {
            outf[(size_t)row * CH + col] = v;
          } else {
            const int b = row >> 11, n = row & (SEQ - 1);
            outb[(((size_t)(b * NH + h) * SEQ + n) << 6) + d] = f2b(v);
          }
        }
      }
    }
  }
}

// ---------------- flash attention (swapped-operand 32x32 MFMA) ----------------
// grid 512 (XCD-swizzled): 16 qt x 32 bh; 4 waves x 32 q rows = 128 q/block.
// S^T = mfma_32x32x16(K, Q): lane owns q = lane&31 -> in-register softmax.
// P -> PV A-frags via cvt_pk + shfl_xor(32) + cndmask (no LDS round trip).
// 3-buffer K/V pipeline with counted vmcnt(4): loads never drain in-loop.
// LDS rows 128B, content XOR-swizzled byte^=(row&7)<<4 (pre-swizzled source).
__device__ __forceinline__ void stage_kv(
    const unsigned short* __restrict__ Kb, const unsigned short* __restrict__ Vb,
    int j0, unsigned char* buf, int wid, int lane) {
#pragma unroll
  for (int is = 0; is < 2; ++is) {
    const int p = wid * 2048 + is * 1024 + lane * 16;
    const int row = p >> 7;
    const int sw = ((p & 127) ^ ((row & 7) << 4)) >> 1;
    gload16(Kb + (size_t)(j0 + row) * HD + sw, buf + wid * 2048 + is * 1024);
    gload16(Vb + (size_t)row * SEQ + j0 + sw, buf + 8192 + wid * 2048 + is * 1024);
  }
}

__global__ __launch_bounds__(256, 2) void attn_kernel(
    const unsigned short* __restrict__ Qh, const unsigned short* __restrict__ Kh,
    const unsigned short* __restrict__ Vt, unsigned short* __restrict__ AO) {
  __shared__ __align__(16) unsigned char smem[49152];  // 3 x (K 8KB + V 8KB)
  const int tid = threadIdx.x, wid = tid >> 6, lane = tid & 63;
  const int l31 = lane & 31, h = lane >> 5;
  const int bid = blockIdx.x;
  const int swz = (bid & 7) * 64 + (bid >> 3);  // bijective: 512 % 8 == 0
  const int qt = swz & 15, bh = swz >> 4;

  const unsigned short* Qb = Qh + ((size_t)bh * SEQ + qt * 128) * HD;
  const unsigned short* Kb = Kh + (size_t)bh * SEQ * HD;
  const unsigned short* Vb = Vt + (size_t)bh * HD * SEQ;

  // ---- issue Q (each wave stages ONLY its own 32 rows, into buf2) ----
#pragma unroll
  for (int is = 0; is < 4; ++is) {
    const int p = wid * 4096 + is * 1024 + lane * 16;
    const int row = p >> 7;
    const int sw = ((p & 127) ^ ((row & 7) << 4)) >> 1;
    gload16(Qb + (size_t)row * HD + sw, smem + 32768 + wid * 4096 + is * 1024);
  }
  // ---- issue K/V tile 0 -> buf0 ----
  stage_kv(Kb, Vb, 0, smem, wid, lane);
  // Q's 4 loads are the oldest; wait until only KV0's 4 remain
  asm volatile("s_waitcnt vmcnt(4)" ::: "memory");

  // Q B-fragments from own rows (no cross-wave dependency)
  bf16x8 qf[4];
  const int qrow = wid * 32 + l31;
#pragma unroll
  for (int ks = 0; ks < 4; ++ks)
    qf[ks] = *(const bf16x8*)(smem + 32768 + qrow * 128 +
                              ((ks * 32 + h * 16) ^ ((qrow & 7) << 4)));
  // Q reads complete before this wave enters the first barrier (so tile-2
  // staging after that barrier can safely overwrite buf2)
  asm volatile("s_waitcnt lgkmcnt(0)" ::: "memory");

  // ---- issue K/V tile 1 -> buf1 ----
  stage_kv(Kb, Vb, 64, smem + 16384, wid, lane);

  f32x16 O[2] = {};
  float m = -1e30f, l = 0.f;

  for (int it = 0; it < 32; ++it) {
    // outstanding: tile it (4, oldest) + tile it+1 (4). Complete tile it,
    // keep it+1 in flight across the barrier (T4: never drain in-loop).
    if (it < 31) asm volatile("s_waitcnt vmcnt(4)" ::: "memory");
    else         asm volatile("s_waitcnt vmcnt(0)" ::: "memory");
    __builtin_amdgcn_s_barrier();
    __builtin_amdgcn_sched_barrier(0);
    if (it + 2 < 32)
      stage_kv(Kb, Vb, (it + 2) * 64, smem + ((it + 2) % 3) * 16384, wid, lane);

    unsigned char* Kc = smem + (it % 3) * 16384;
    unsigned char* Vc = Kc + 8192;

    // ---- S^T = K @ Q^T : st[kb] covers keys 32kb..32kb+31 for q=l31 ----
    f32x16 st[2] = {};
    __builtin_amdgcn_s_setprio(1);
#pragma unroll
    for (int kb = 0; kb < 2; ++kb) {
#pragma unroll
      for (int ks = 0; ks < 4; ++ks) {
        const int krow = kb * 32 + l31;
        const bf16x8 kf = *(const bf16x8*)(Kc + krow * 128 +
                                           ((ks * 32 + h * 16) ^ ((krow & 7) << 4)));
        st[kb] = __builtin_amdgcn_mfma_f32_32x32x16_bf16(kf, qf[ks], st[kb], 0, 0, 0);
      }
    }
    __builtin_amdgcn_s_setprio(0);

    // ---- in-register online softmax (base-2 domain), defer-max THR=8 ----
    float t[8];
#pragma unroll
    for (int i = 0; i < 8; ++i)
      t[i] = fmaxf(fmaxf(st[0][i], st[0][i + 8]), fmaxf(st[1][i], st[1][i + 8]));
#pragma unroll
    for (int i = 0; i < 4; ++i) t[i] = fmaxf(t[i], t[i + 4]);
    float pmax = fmaxf(fmaxf(t[0], t[1]), fmaxf(t[2], t[3]));
    pmax = fmaxf(pmax, __shfl_xor(pmax, 32));
    if (__any(pmax > m + 8.f)) {
      const float mnew = fmaxf(m, pmax);
      const float alpha = exp2f(m - mnew);
#pragma unroll
      for (int r = 0; r < 16; ++r) {
        const int qO = (r & 3) + 8 * (r >> 2) + 4 * h;
        const float aO = __shfl(alpha, qO);
        O[0][r] *= aO;
        O[1][r] *= aO;
      }
      l *= alpha;
      m = mnew;
    }
#pragma unroll
    for (int kb = 0; kb < 2; ++kb)
#pragma unroll
      for (int i = 0; i < 16; ++i) st[kb][i] = exp2f(st[kb][i] - m);
    float s[8];
#pragma unroll
    for (int i = 0; i < 8; ++i)
      s[i] = (st[0][i] + st[0][i + 8]) + (st[1][i] + st[1][i + 8]);
#pragma unroll
    for (int i = 0; i < 4; ++i) s[i] += s[i + 4];
    float rs = (s[0] + s[1]) + (s[2] + s[3]);
    rs += __shfl_xor(rs, 32);
    l += rs;

    // ---- pack P to bf16 pairs ----
    unsigned int pk[2][8];
#pragma unroll
    for (int kb = 0; kb < 2; ++kb)
#pragma unroll
      for (int j = 0; j < 8; ++j)
        pk[kb][j] = cvtpk(st[kb][2 * j], st[kb][2 * j + 1]);

    // ---- build PV A-frags: lane needs P[q=l31][16kk + 8h + e] ----
    __builtin_amdgcn_s_setprio(1);
#pragma unroll
    for (int kk = 0; kk < 4; ++kk) {
      const int kb = kk >> 1, j0 = (kk & 1) * 4;
      const unsigned int p0 = pk[kb][j0 + 0], p1 = pk[kb][j0 + 1];
      const unsigned int p2 = pk[kb][j0 + 2], p3 = pk[kb][j0 + 3];
      const unsigned int u0 = h ? p0 : p2;
      const unsigned int u1 = h ? p1 : p3;
      const unsigned int su0 = __shfl_xor(u0, 32);
      const unsigned int su1 = __shfl_xor(u1, 32);
      const unsigned int d0 = h ? su0 : p0;
      const unsigned int d1 = h ? su1 : p1;
      const unsigned int d2 = h ? p2 : su0;
      const unsigned int d3 = h ? p3 : su1;
      uint4 aw = make_uint4(d0, d1, d2, d3);
      const bf16x8 af = *(const bf16x8*)&aw;
#pragma unroll
      for (int db = 0; db < 2; ++db) {
        const int vrow = db * 32 + l31;
        const bf16x8 vf = *(const bf16x8*)(Vc + vrow * 128 +
                                           ((kk * 32 + h * 16) ^ ((vrow & 7) << 4)));
        O[db] = __builtin_amdgcn_mfma_f32_32x32x16_bf16(af, vf, O[db], 0, 0, 0);
      }
    }
    __builtin_amdgcn_s_setprio(0);
  }

  // ---- epilogue: O/l, write bf16 to [b][n][head*64+d] ----
  const int b = bh >> 4, hh = bh & 15;
#pragma unroll
  for (int r = 0; r < 16; ++r) {
    const int qO = (r & 3) + 8 * (r >> 2) + 4 * h;
    const float lO = __shfl(l, qO);
    const float inv = 1.f / lO;
    const int n = qt * 128 + wid * 32 + qO;
    const size_t base = ((size_t)(b * SEQ + n)) * CH + hh * HD;
    AO[base + l31] = f2b(O[0][r] * inv);
    AO[base + 32 + l31] = f2b(O[1][r] * inv);
  }
}

extern "C" void kernel_launch(void* const* d_in, const int* in_sizes, int n_in,
                              void* d_out, int out_size, void* d_ws, size_t ws_size,
                              hipStream_t stream) {
  (void)in_sizes; (void)n_in; (void)out_size; (void)ws_size;
  const float* q  = (const float*)d_in[0];
  const float* k  = (const float*)d_in[1];
  const float* v  = (const float*)d_in[2];
  const float* wq = (const float*)d_in[3];
  const float* bq = (const float*)d_in[4];
  const float* wk = (const float*)d_in[5];
  const float* bk = (const float*)d_in[6];
  const float* wv = (const float*)d_in[7];
  const float* bv = (const float*)d_in[8];
  const float* wo = (const float*)d_in[9];
  const float* bo = (const float*)d_in[10];

  unsigned char* ws = (unsigned char*)d_ws;
  const size_t MB8 = 8u << 20;
  unsigned short* qb  = (unsigned short*)(ws + 0 * MB8);
  unsigned short* kb  = (unsigned short*)(ws + 1 * MB8);
  unsigned short* vb  = (unsigned short*)(ws + 2 * MB8);
  unsigned short* wqb = (unsigned short*)(ws + 3 * MB8);
  unsigned short* wkb = (unsigned short*)(ws + 3 * MB8 + 1 * 2097152);
  unsigned short* wvb = (unsigned short*)(ws + 3 * MB8 + 2 * 2097152);
  unsigned short* wob = (unsigned short*)(ws + 3 * MB8 + 3 * 2097152);
  unsigned short* Qh  = (unsigned short*)(ws + 4 * MB8);
  unsigned short* Kh  = (unsigned short*)(ws + 5 * MB8);
  unsigned short* VtT = kb;  // kb dead after QK proj (V proj launched after)
  unsigned short* AO  = qb;  // qb dead after QK proj
  float* out = (float*)d_out;

  CvtArgs ca;
  ca.src[0] = q;  ca.dst[0] = qb;  ca.n4[0] = TOK * CH / 4;
  ca.src[1] = k;  ca.dst[1] = kb;  ca.n4[1] = TOK * CH / 4;
  ca.src[2] = v;  ca.dst[2] = vb;  ca.n4[2] = TOK * CH / 4;
  ca.src[3] = wq; ca.dst[3] = wqb; ca.n4[3] = CH * CH / 4;
  ca.src[4] = wk; ca.dst[4] = wkb; ca.n4[4] = CH * CH / 4;
  ca.src[5] = wv; ca.dst[5] = wvb; ca.n4[5] = CH * CH / 4;
  ca.src[6] = wo; ca.dst[6] = wob; ca.n4[6] = CH * CH / 4;
  cvt_kernel<<<dim3(1024, 7), 256, 0, stream>>>(ca);

  ProjArgs qk;
  qk.X[0] = qb;  qk.W[0] = wqb; qk.bias[0] = bq; qk.outb[0] = Qh; qk.mode[0] = 0;
  qk.X[1] = kb;  qk.W[1] = wkb; qk.bias[1] = bk; qk.outb[1] = Kh; qk.mode[1] = 1;
  qk.outf = nullptr;
  proj_kernel<<<dim3(32, 16, 2), 256, 0, stream>>>(qk);

  ProjArgs vp;
  vp.X[0] = vb;  vp.W[0] = wvb; vp.bias[0] = bv; vp.outb[0] = VtT; vp.mode[0] = 3;
  vp.X[1] = vb;  vp.W[1] = wvb; vp.bias[1] = bv; vp.outb[1] = VtT; vp.mode[1] = 3;
  vp.outf = nullptr;
  proj_kernel<<<dim3(32, 16, 1), 256, 0, stream>>>(vp);

  attn_kernel<<<dim3(512), 256, 0, stream>>>(Qh, Kh, VtT, AO);

  ProjArgs op;
  op.X[0] = AO; op.W[0] = wob; op.bias[0] = bo; op.outb[0] = nullptr; op.mode[0] = 2;
  op.X[1] = AO; op.W[1] = wob; op.bias[1] = bo; op.outb[1] = nullptr; op.mode[1] = 2;
  op.outf = out;
  proj_kernel<<<dim3(32, 16, 1), 256, 0, stream>>>(op);
}

// Round 7
// 134.397 us; speedup vs baseline: 2.1784x; 1.1133x over previous
//
#include <hip/hip_runtime.h>

// MHA b=2 n=2048 c=1024 h=16 d=64. bf16 MFMA everywhere, f32 accum.
// R7: in-block split-K attention: 8 waves = 2 key-groups x 4 q-waves;
//     f32 LDS combine (no global partials, single bf16 rounding);
//     race-free 2-buffer schedule (wait -> barrier -> compute -> barrier -> stage).
// ws (48MB): qb(8M) kb(8M) vb(8M) w*(4x2M) Qh(8M) Kh(8M); Vt=kb, AO=qb.

typedef float f32x4 __attribute__((ext_vector_type(4)));
typedef float f32x16 __attribute__((ext_vector_type(16)));
typedef __bf16 bf16x8 __attribute__((ext_vector_type(8)));

#define SEQ 2048
#define CH 1024
#define NH 16
#define HD 64
#define TOK 4096
// 0.125 (d^-1/2) * log2(e): fold softmax base-2 conversion into Q
#define QSCALE 0.18033688011112042f

__device__ __forceinline__ unsigned short f2b(float f) {
  unsigned int u = __float_as_uint(f);
  u = (u + 0x7FFFu + ((u >> 16) & 1u)) >> 16;  // RNE
  return (unsigned short)u;
}

__device__ __forceinline__ float fexp2(float x) {  // guaranteed single v_exp_f32
  float r;
  asm("v_exp_f32 %0, %1" : "=v"(r) : "v"(x));
  return r;
}

__device__ __forceinline__ unsigned int cvtpk(float lo, float hi) {
  unsigned int r;
  asm("v_cvt_pk_bf16_f32 %0, %1, %2" : "=v"(r) : "v"(lo), "v"(hi));
  return r;
}

__device__ __forceinline__ void gload16(const void* g, void* l) {
  __builtin_amdgcn_global_load_lds(
      (const __attribute__((address_space(1))) unsigned int*)g,
      (__attribute__((address_space(3))) unsigned int*)l, 16, 0, 0);
}

// ---------------- f32 -> bf16 conversion ----------------
struct CvtArgs {
  const float* src[7];
  unsigned short* dst[7];
  int n4[7];
};

__global__ __launch_bounds__(256) void cvt_kernel(CvtArgs a) {
  const int s = blockIdx.y;
  const int n4 = a.n4[s];
  const float4* __restrict__ src = (const float4*)a.src[s];
  unsigned short* __restrict__ dst = a.dst[s];
  const int stride = gridDim.x * blockDim.x;
  for (int i = blockIdx.x * blockDim.x + threadIdx.x; i < n4; i += stride) {
    float4 w = src[i];
    ushort4 o;
    o.x = f2b(w.x); o.y = f2b(w.y); o.z = f2b(w.z); o.w = f2b(w.w);
    *(ushort4*)(dst + 4 * (size_t)i) = o;
  }
}

// ---------------- GEMM: X[4096,1024] @ W^T + bias, 128x64 tile ----------------
// mode 0: bf16 head layout [bh][n][d], scaled by QSCALE (Q)
// mode 1: bf16 head layout (K)
// mode 2: f32 flat [4096][1024] (output projection)
// mode 3: bf16 transposed head layout [bh][d][n] (V^T)
struct ProjArgs {
  const unsigned short* X[2];
  const unsigned short* W[2];
  const float* bias[2];
  unsigned short* outb[2];
  float* outf;
  int mode[2];
};

// stage one K-step (BK=32): A 128x32 (8KB) + B 64x32 (4KB); 3 gload16/lane
__device__ __forceinline__ void proj_stage(
    const unsigned short* __restrict__ X, const unsigned short* __restrict__ W,
    int mt, int nt, int k0, unsigned char* buf, int wid, int lane) {
#pragma unroll
  for (int is = 0; is < 2; ++is) {
    const int p = (wid * 2 + is) * 1024 + lane * 16;
    gload16(X + (size_t)(mt * 128 + (p >> 6)) * CH + k0 + ((p & 63) >> 1),
            buf + (wid * 2 + is) * 1024);
  }
  {
    const int p = wid * 1024 + lane * 16;
    gload16(W + (size_t)(nt * 64 + (p >> 6)) * CH + k0 + ((p & 63) >> 1),
            buf + 8192 + wid * 1024);
  }
}

__global__ __launch_bounds__(256, 4) void proj_kernel(ProjArgs a) {
  constexpr int BUFB = 8192 + 4096;  // A + B bytes per buffer
  __shared__ __align__(16) unsigned char smem[3 * BUFB];
  const int z = blockIdx.z;
  const unsigned short* __restrict__ X = a.X[z];
  const unsigned short* __restrict__ W = a.W[z];
  const float* __restrict__ bias = a.bias[z];
  unsigned short* __restrict__ outb = a.outb[z];
  float* __restrict__ outf = a.outf;
  const int mode = a.mode[z];
  const int tid = threadIdx.x, wid = tid >> 6, lane = tid & 63;
  const int wm = wid >> 1, wn = wid & 1;
  const int mt = blockIdx.x, nt = blockIdx.y;
  const int l15 = lane & 15, l4 = lane >> 4;

  // bias loads pinned BEFORE stage(0): they retire early and never perturb
  // the in-loop vmcnt counting (they are oldest if still outstanding).
  float bvv[2];
#pragma unroll
  for (int nj = 0; nj < 2; ++nj)
    bvv[nj] = bias[nt * 64 + wn * 32 + nj * 16 + l15];

  f32x4 acc[4][2] = {};

  proj_stage(X, W, mt, nt, 0, smem, wid, lane);
  proj_stage(X, W, mt, nt, 32, smem + BUFB, wid, lane);

  for (int s = 0; s < 32; ++s) {
    // tile s done (its 3 loads are this wave's oldest); keep s+1 in flight
    if (s < 31) asm volatile("s_waitcnt vmcnt(3)" ::: "memory");
    else        asm volatile("s_waitcnt vmcnt(0)" ::: "memory");
    __builtin_amdgcn_s_barrier();
    __builtin_amdgcn_sched_barrier(0);
    if (s + 2 < 32)
      proj_stage(X, W, mt, nt, (s + 2) * 32, smem + ((s + 2) % 3) * BUFB, wid, lane);

    unsigned char* Al = smem + (s % 3) * BUFB;
    unsigned char* Bl = Al + 8192;
    bf16x8 af[4], bfr[2];
#pragma unroll
    for (int mi = 0; mi < 4; ++mi)
      af[mi] = *(const bf16x8*)(Al + (wm * 64 + mi * 16 + l15) * 64 + l4 * 16);
#pragma unroll
    for (int nj = 0; nj < 2; ++nj)
      bfr[nj] = *(const bf16x8*)(Bl + (wn * 32 + nj * 16 + l15) * 64 + l4 * 16);
    __builtin_amdgcn_s_setprio(1);
#pragma unroll
    for (int mi = 0; mi < 4; ++mi)
#pragma unroll
      for (int nj = 0; nj < 2; ++nj)
        acc[mi][nj] = __builtin_amdgcn_mfma_f32_16x16x32_bf16(af[mi], bfr[nj], acc[mi][nj], 0, 0, 0);
    __builtin_amdgcn_s_setprio(0);
  }

  const int row0 = mt * 128 + wm * 64;
  const int col0 = nt * 64 + wn * 32;
#pragma unroll
  for (int nj = 0; nj < 2; ++nj) {
    const int col = col0 + nj * 16 + l15;
    const float bv = bvv[nj];
    const int h = col >> 6, d = col & 63;
    if (mode == 3) {
      // V^T: pack 4 consecutive n per (mi,nj)
#pragma unroll
      for (int mi = 0; mi < 4; ++mi) {
        const int row = row0 + mi * 16 + l4 * 4;
        const int b = row >> 11, n = row & (SEQ - 1);
        ushort4 o;
        o.x = f2b(acc[mi][nj][0] + bv);
        o.y = f2b(acc[mi][nj][1] + bv);
        o.z = f2b(acc[mi][nj][2] + bv);
        o.w = f2b(acc[mi][nj][3] + bv);
        *(ushort4*)(outb + ((size_t)(b * NH + h) * HD + d) * SEQ + n) = o;
      }
    } else {
#pragma unroll
      for (int mi = 0; mi < 4; ++mi) {
#pragma unroll
        for (int r = 0; r < 4; ++r) {
          const int row = row0 + mi * 16 + l4 * 4 + r;
          float v = acc[mi][nj][r] + bv;
          if (mode == 0) v *= QSCALE;
          if (mode == 2) {
            outf[(size_t)row * CH + col] = v;
          } else {
            const int b = row >> 11, n = row & (SEQ - 1);
            outb[(((size_t)(b * NH + h) * SEQ + n) << 6) + d] = f2b(v);
          }
        }
      }
    }
  }
}

// ---------------- flash attention: in-block split-K, 8 waves ----------------
// grid 512 (XCD-swizzled): 16 qt x 32 bh. Waves 0-3 = key group 0 (keys
// [0,1024)), waves 4-7 = group 1 ([1024,2048)); wave (grp,wq) owns q rows
// [qt*128+wq*32, +32). Swapped-operand 32x32 MFMA; in-register softmax;
// per-group 2-buffer KV pipeline; f32 LDS combine of the two groups.
// LDS rows 128B, content XOR-swizzled byte^=(row&7)<<4 (pre-swizzled source).
__device__ __forceinline__ void stage_kv(
    const unsigned short* __restrict__ Kb, const unsigned short* __restrict__ Vb,
    int j0, unsigned char* buf, int ws3, int lane) {
#pragma unroll
  for (int is = 0; is < 2; ++is) {
    const int p = ws3 * 2048 + is * 1024 + lane * 16;
    const int row = p >> 7;
    const int sw = ((p & 127) ^ ((row & 7) << 4)) >> 1;
    gload16(Kb + (size_t)(j0 + row) * HD + sw, buf + ws3 * 2048 + is * 1024);
    gload16(Vb + (size_t)row * SEQ + j0 + sw, buf + 8192 + ws3 * 2048 + is * 1024);
  }
}

__global__ __launch_bounds__(512, 4) void attn_kernel(
    const unsigned short* __restrict__ Qh, const unsigned short* __restrict__ Kh,
    const unsigned short* __restrict__ Vt, unsigned short* __restrict__ AO) {
  // [G0 KV 32KB][G1 KV 32KB][Q 16KB]; combine slots reuse [0,35840) post-loop
  __shared__ __align__(16) unsigned char smem[81920];
  const int tid = threadIdx.x, wid = tid >> 6, lane = tid & 63;
  const int l31 = lane & 31, h = lane >> 5;
  const int grp = wid >> 2, wq = wid & 3;
  const int bid = blockIdx.x;
  const int swz = (bid & 7) * 64 + (bid >> 3);  // bijective: 512 % 8 == 0
  const int qt = swz & 15, bh = swz >> 4;

  const unsigned short* Qb = Qh + ((size_t)bh * SEQ + qt * 128) * HD;
  const unsigned short* Kb = Kh + (size_t)bh * SEQ * HD;
  const unsigned short* Vb = Vt + (size_t)bh * HD * SEQ;
  unsigned char* kvb = smem + grp * 32768;  // this group's 2 x 16KB buffers
  unsigned char* Qreg = smem + 65536;
  const int jbase = grp * 16;

  // ---- stage own 32 Q rows (waves wq and wq+4 write identical bytes —
  //      benign double-DMA; keeps prologue barrier-free, vmcnt exact) ----
#pragma unroll
  for (int is = 0; is < 4; ++is) {
    const int p = wq * 4096 + is * 1024 + lane * 16;
    const int row = p >> 7;
    const int sw = ((p & 127) ^ ((row & 7) << 4)) >> 1;
    gload16(Qb + (size_t)row * HD + sw, Qreg + wq * 4096 + is * 1024);
  }
  // ---- K/V tile 0 -> buf0 ----
  stage_kv(Kb, Vb, jbase * 64, kvb, wq, lane);
  asm volatile("s_waitcnt vmcnt(4)" ::: "memory");  // own Q loads complete

  bf16x8 qf[4];
  const int qrow = wq * 32 + l31;
#pragma unroll
  for (int ks = 0; ks < 4; ++ks)
    qf[ks] = *(const bf16x8*)(Qreg + qrow * 128 +
                              ((ks * 32 + h * 16) ^ ((qrow & 7) << 4)));
  // (Q region is never overwritten until the post-loop combine; compiler
  //  inserts the lgkmcnt dependency before first MFMA use of qf.)

  // ---- K/V tile 1 -> buf1 ----
  stage_kv(Kb, Vb, (jbase + 1) * 64, kvb + 16384, wq, lane);

  f32x16 O[2] = {};
  float m = -1e30f, l = 0.f;

  for (int it = 0; it < 16; ++it) {
    // complete OWN tile-it loads, then barrier => ALL waves' tile-it loads
    // complete (every wave waited before arriving). Race-free by construction.
    if (it < 15) asm volatile("s_waitcnt vmcnt(4)" ::: "memory");
    else         asm volatile("s_waitcnt vmcnt(0)" ::: "memory");
    __builtin_amdgcn_s_barrier();
    __builtin_amdgcn_sched_barrier(0);

    unsigned char* Kc = kvb + ((it & 1) << 14);
    unsigned char* Vc = Kc + 8192;

    // ---- S^T = K @ Q^T : st[kb] covers keys 32kb..32kb+31 for q=l31 ----
    f32x16 st[2] = {};
    __builtin_amdgcn_s_setprio(1);
#pragma unroll
    for (int kb = 0; kb < 2; ++kb) {
#pragma unroll
      for (int ks = 0; ks < 4; ++ks) {
        const int krow = kb * 32 + l31;
        const bf16x8 kf = *(const bf16x8*)(Kc + krow * 128 +
                                           ((ks * 32 + h * 16) ^ ((krow & 7) << 4)));
        st[kb] = __builtin_amdgcn_mfma_f32_32x32x16_bf16(kf, qf[ks], st[kb], 0, 0, 0);
      }
    }
    __builtin_amdgcn_s_setprio(0);

    // ---- in-register online softmax (base-2 domain), defer-max THR=8 ----
    float t[8];
#pragma unroll
    for (int i = 0; i < 8; ++i)
      t[i] = fmaxf(fmaxf(st[0][i], st[0][i + 8]), fmaxf(st[1][i], st[1][i + 8]));
#pragma unroll
    for (int i = 0; i < 4; ++i) t[i] = fmaxf(t[i], t[i + 4]);
    float pmax = fmaxf(fmaxf(t[0], t[1]), fmaxf(t[2], t[3]));
    pmax = fmaxf(pmax, __shfl_xor(pmax, 32));
    if (__any(pmax > m + 8.f)) {
      const float mnew = fmaxf(m, pmax);
      const float alpha = fexp2(m - mnew);
#pragma unroll
      for (int r = 0; r < 16; ++r) {
        const int qO = (r & 3) + 8 * (r >> 2) + 4 * h;
        const float aO = __shfl(alpha, qO);
        O[0][r] *= aO;
        O[1][r] *= aO;
      }
      l *= alpha;
      m = mnew;
    }
#pragma unroll
    for (int kb = 0; kb < 2; ++kb)
#pragma unroll
      for (int i = 0; i < 16; ++i) st[kb][i] = fexp2(st[kb][i] - m);
    float s[8];
#pragma unroll
    for (int i = 0; i < 8; ++i)
      s[i] = (st[0][i] + st[0][i + 8]) + (st[1][i] + st[1][i + 8]);
#pragma unroll
    for (int i = 0; i < 4; ++i) s[i] += s[i + 4];
    float rs = (s[0] + s[1]) + (s[2] + s[3]);
    rs += __shfl_xor(rs, 32);
    l += rs;

    // ---- pack P to bf16 pairs ----
    unsigned int pk[2][8];
#pragma unroll
    for (int kb = 0; kb < 2; ++kb)
#pragma unroll
      for (int j = 0; j < 8; ++j)
        pk[kb][j] = cvtpk(st[kb][2 * j], st[kb][2 * j + 1]);

    // ---- build PV A-frags: lane needs P[q=l31][16kk + 8h + e] ----
    __builtin_amdgcn_s_setprio(1);
#pragma unroll
    for (int kk = 0; kk < 4; ++kk) {
      const int kb = kk >> 1, j0 = (kk & 1) * 4;
      const unsigned int p0 = pk[kb][j0 + 0], p1 = pk[kb][j0 + 1];
      const unsigned int p2 = pk[kb][j0 + 2], p3 = pk[kb][j0 + 3];
      const unsigned int u0 = h ? p0 : p2;
      const unsigned int u1 = h ? p1 : p3;
      const unsigned int su0 = __shfl_xor(u0, 32);
      const unsigned int su1 = __shfl_xor(u1, 32);
      const unsigned int d0 = h ? su0 : p0;
      const unsigned int d1 = h ? su1 : p1;
      const unsigned int d2 = h ? p2 : su0;
      const unsigned int d3 = h ? p3 : su1;
      uint4 aw = make_uint4(d0, d1, d2, d3);
      const bf16x8 af = *(const bf16x8*)&aw;
#pragma unroll
      for (int db = 0; db < 2; ++db) {
        const int vrow = db * 32 + l31;
        const bf16x8 vf = *(const bf16x8*)(Vc + vrow * 128 +
                                           ((kk * 32 + h * 16) ^ ((vrow & 7) << 4)));
        O[db] = __builtin_amdgcn_mfma_f32_32x32x16_bf16(af, vf, O[db], 0, 0, 0);
      }
    }
    __builtin_amdgcn_s_setprio(0);

    // all waves done reading buf[it&1]; stage tile it+2 into it
    __builtin_amdgcn_s_barrier();
    if (it + 2 < 16)
      stage_kv(Kb, Vb, (jbase + it + 2) * 64, Kc, wq, lane);
  }
  // post-loop: last tail barrier passed by all waves -> KV region free

  // ---- combine: group 1 dumps (O,m,l) f32 to LDS; group 0 merges ----
  // slot per wq: 64 lanes x 17 float2 (136B, 4-way-max conflict) + 32 (m,l)
  float2* slotO = (float2*)(smem + wq * 8960);
  float2* slotML = (float2*)(smem + wq * 8960 + 8704);
  if (grp == 1) {
    float2* dst = slotO + lane * 17;
#pragma unroll
    for (int i = 0; i < 8; ++i) dst[i] = make_float2(O[0][2 * i], O[0][2 * i + 1]);
#pragma unroll
    for (int i = 0; i < 8; ++i) dst[8 + i] = make_float2(O[1][2 * i], O[1][2 * i + 1]);
    if (h == 0) slotML[l31] = make_float2(m, l);
  }
  __builtin_amdgcn_s_barrier();
  if (grp == 0) {
    const float* src = (const float*)(slotO + lane * 17);
    const float2 ml1 = slotML[l31];
    const float mm = fmaxf(m, ml1.x);
    const float a0 = fexp2(m - mm), a1 = fexp2(ml1.x - mm);
    const float inv = 1.f / (a0 * l + a1 * ml1.y);
    const float w0 = a0 * inv, w1 = a1 * inv;
    const int b = bh >> 4, hh = bh & 15;
#pragma unroll
    for (int r = 0; r < 16; ++r) {
      const int qO = (r & 3) + 8 * (r >> 2) + 4 * h;
      const float s0 = __shfl(w0, qO), s1 = __shfl(w1, qO);
      const int n = qt * 128 + wq * 32 + qO;
      const size_t base = ((size_t)(b * SEQ + n)) * CH + hh * HD;
      AO[base + l31] = f2b(O[0][r] * s0 + src[r] * s1);
      AO[base + 32 + l31] = f2b(O[1][r] * s0 + src[16 + r] * s1);
    }
  }
}

extern "C" void kernel_launch(void* const* d_in, const int* in_sizes, int n_in,
                              void* d_out, int out_size, void* d_ws, size_t ws_size,
                              hipStream_t stream) {
  (void)in_sizes; (void)n_in; (void)out_size; (void)ws_size;
  const float* q  = (const float*)d_in[0];
  const float* k  = (const float*)d_in[1];
  const float* v  = (const float*)d_in[2];
  const float* wq = (const float*)d_in[3];
  const float* bq = (const float*)d_in[4];
  const float* wk = (const float*)d_in[5];
  const float* bk = (const float*)d_in[6];
  const float* wv = (const float*)d_in[7];
  const float* bv = (const float*)d_in[8];
  const float* wo = (const float*)d_in[9];
  const float* bo = (const float*)d_in[10];

  unsigned char* ws = (unsigned char*)d_ws;
  const size_t MB8 = 8u << 20;
  unsigned short* qb  = (unsigned short*)(ws + 0 * MB8);
  unsigned short* kb  = (unsigned short*)(ws + 1 * MB8);
  unsigned short* vb  = (unsigned short*)(ws + 2 * MB8);
  unsigned short* wqb = (unsigned short*)(ws + 3 * MB8);
  unsigned short* wkb = (unsigned short*)(ws + 3 * MB8 + 1 * 2097152);
  unsigned short* wvb = (unsigned short*)(ws + 3 * MB8 + 2 * 2097152);
  unsigned short* wob = (unsigned short*)(ws + 3 * MB8 + 3 * 2097152);
  unsigned short* Qh  = (unsigned short*)(ws + 4 * MB8);
  unsigned short* Kh  = (unsigned short*)(ws + 5 * MB8);
  unsigned short* VtT = kb;  // kb dead after QK proj (V proj launched after)
  unsigned short* AO  = qb;  // qb dead after QK proj
  float* out = (float*)d_out;

  CvtArgs ca;
  ca.src[0] = q;  ca.dst[0] = qb;  ca.n4[0] = TOK * CH / 4;
  ca.src[1] = k;  ca.dst[1] = kb;  ca.n4[1] = TOK * CH / 4;
  ca.src[2] = v;  ca.dst[2] = vb;  ca.n4[2] = TOK * CH / 4;
  ca.src[3] = wq; ca.dst[3] = wqb; ca.n4[3] = CH * CH / 4;
  ca.src[4] = wk; ca.dst[4] = wkb; ca.n4[4] = CH * CH / 4;
  ca.src[5] = wv; ca.dst[5] = wvb; ca.n4[5] = CH * CH / 4;
  ca.src[6] = wo; ca.dst[6] = wob; ca.n4[6] = CH * CH / 4;
  cvt_kernel<<<dim3(1024, 7), 256, 0, stream>>>(ca);

  ProjArgs qk;
  qk.X[0] = qb;  qk.W[0] = wqb; qk.bias[0] = bq; qk.outb[0] = Qh; qk.mode[0] = 0;
  qk.X[1] = kb;  qk.W[1] = wkb; qk.bias[1] = bk; qk.outb[1] = Kh; qk.mode[1] = 1;
  qk.outf = nullptr;
  proj_kernel<<<dim3(32, 16, 2), 256, 0, stream>>>(qk);

  ProjArgs vp;
  vp.X[0] = vb;  vp.W[0] = wvb; vp.bias[0] = bv; vp.outb[0] = VtT; vp.mode[0] = 3;
  vp.X[1] = vb;  vp.W[1] = wvb; vp.bias[1] = bv; vp.outb[1] = VtT; vp.mode[1] = 3;
  vp.outf = nullptr;
  proj_kernel<<<dim3(32, 16, 1), 256, 0, stream>>>(vp);

  attn_kernel<<<dim3(512), 512, 0, stream>>>(Qh, Kh, VtT, AO);

  ProjArgs op;
  op.X[0] = AO; op.W[0] = wob; op.bias[0] = bo; op.outb[0] = nullptr; op.mode[0] = 2;
  op.X[1] = AO; op.W[1] = wob; op.bias[1] = bo; op.outb[1] = nullptr; op.mode[1] = 2;
  op.outf = out;
  proj_kernel<<<dim3(32, 16, 1), 256, 0, stream>>>(op);
}